// Round 1
// baseline (1449.578 us; speedup 1.0000x reference)
//
#include <hip/hip_runtime.h>
#include <math.h>

#define DEV_INLINE __device__ __forceinline__

DEV_INLINE float relu_f(float v) { return v > 0.f ? v : 0.f; }

DEV_INLINE void fma4(float4& a, float s, const float4& v) {
    a.x += s * v.x; a.y += s * v.y; a.z += s * v.z; a.w += s * v.w;
}

// ---------------------------------------------------------------------------
// conv1: x[32,152,152,3] * W[11,11,3,32] + b, relu -> y[32,142,142,32]
// block 256 (16ty x 16tx), tile 16 oh x 32 ow, thread: 2 ow x 32 oc.
// Weights are read straight from global with wave-uniform indices (loop
// counters only) -> compiler scalarizes to s_load through the constant
// cache; v_fmac takes the SGPR operand directly. LDS holds only the x tile
// (13.1 KB) -> ~5 waves/SIMD instead of 2.
// ---------------------------------------------------------------------------
__global__ __launch_bounds__(256) void k_conv1(
    const float* __restrict__ x, const float* __restrict__ W,
    const float* __restrict__ b, float* __restrict__ y)
{
    __shared__ float sx[26 * 42 * 3];        // 3276 floats = 13.1 KB
    const int n   = blockIdx.z;
    const int oh0 = blockIdx.y * 16;
    const int ow0 = blockIdx.x * 32;
    const int tid = threadIdx.x;

    const float* xn = x + (size_t)n * 152 * 152 * 3;
    for (int i = tid; i < 26 * 42 * 3; i += 256) {
        int c = i % 3; int t = i / 3; int col = t % 42; int row = t / 42;
        int r  = oh0 + row; if (r > 151) r = 151;
        int cc = ow0 + col; if (cc > 151) cc = 151;
        sx[i] = xn[(r * 152 + cc) * 3 + c];
    }
    __syncthreads();

    const int ty = tid >> 4, tx = tid & 15;
    float acc[2][32];
#pragma unroll
    for (int p = 0; p < 2; ++p)
#pragma unroll
        for (int j = 0; j < 32; ++j) acc[p][j] = 0.f;

    for (int kh = 0; kh < 11; ++kh) {
        const float* sxr = &sx[((ty + kh) * 42 + tx) * 3];
        const float* wr  = W + kh * (11 * 3 * 32);
        for (int kw = 0; kw < 11; ++kw) {
#pragma unroll
            for (int ic = 0; ic < 3; ++ic) {
                float x0 = sxr[kw * 3 + ic];
                float x1 = sxr[(kw + 16) * 3 + ic];
                const float4* wp4 = (const float4*)&wr[(kw * 3 + ic) * 32];
#pragma unroll
                for (int j4 = 0; j4 < 8; ++j4) {
                    float4 w = wp4[j4];
                    acc[0][j4 * 4 + 0] += x0 * w.x;
                    acc[0][j4 * 4 + 1] += x0 * w.y;
                    acc[0][j4 * 4 + 2] += x0 * w.z;
                    acc[0][j4 * 4 + 3] += x0 * w.w;
                    acc[1][j4 * 4 + 0] += x1 * w.x;
                    acc[1][j4 * 4 + 1] += x1 * w.y;
                    acc[1][j4 * 4 + 2] += x1 * w.z;
                    acc[1][j4 * 4 + 3] += x1 * w.w;
                }
            }
        }
    }

#pragma unroll
    for (int p = 0; p < 2; ++p) {
        int oh = oh0 + ty, ow = ow0 + tx + p * 16;
        if (oh < 142 && ow < 142) {
            float* yp = y + (((size_t)n * 142 + oh) * 142 + ow) * 32;
#pragma unroll
            for (int j = 0; j < 32; ++j) yp[j] = relu_f(acc[p][j] + b[j]);
        }
    }
}

// ---------------------------------------------------------------------------
// maxpool 3x3 s2: y1[32,142,142,32] -> y2[32,70,70,32]
// ---------------------------------------------------------------------------
__global__ void k_pool(const float* __restrict__ x, float* __restrict__ y)
{
    int idx = blockIdx.x * 256 + threadIdx.x;  // over 32*70*70*8 (c in float4s)
    if (idx >= 32 * 70 * 70 * 8) return;
    int c4 = idx & 7; int t = idx >> 3;
    int pw = t % 70; t /= 70; int ph = t % 70; int n = t / 70;
    const float* xp = x + (((size_t)n * 142 + ph * 2) * 142 + pw * 2) * 32 + c4 * 4;
    float4 m = make_float4(-1e30f, -1e30f, -1e30f, -1e30f);
#pragma unroll
    for (int r = 0; r < 3; ++r) {
#pragma unroll
        for (int cc = 0; cc < 3; ++cc) {
            float4 v = *(const float4*)(xp + ((size_t)r * 142 + cc) * 32);
            m.x = fmaxf(m.x, v.x); m.y = fmaxf(m.y, v.y);
            m.z = fmaxf(m.z, v.z); m.w = fmaxf(m.w, v.w);
        }
    }
    *(float4*)(y + (size_t)idx * 4) = m;
}

// ---------------------------------------------------------------------------
// conv3: y2[32,70,70,32] * W[9,9,32,16] + b, relu -> y3[32,62,62,16]
// block 128 (8ty x 16tx), tile 8 oh x 32 ow, thread: 2 ow x 16 oc.
// ic chunks of 8; only the x tile lives in LDS (20.5 KB). Weights read
// from global with wave-uniform indices -> scalar loads.
// ---------------------------------------------------------------------------
__global__ __launch_bounds__(128) void k_conv3(
    const float* __restrict__ x, const float* __restrict__ W,
    const float* __restrict__ bias, float* __restrict__ y)
{
    __shared__ float sx[16 * 40 * 8];   // 5120 floats = 20.5 KB
    const int n   = blockIdx.z;
    const int oh0 = blockIdx.y * 8;
    const int ow0 = blockIdx.x * 32;
    const int tid = threadIdx.x;
    const int ty = tid >> 4, tx = tid & 15;
    const float* xn = x + (size_t)n * 70 * 70 * 32;

    float acc[2][16];
#pragma unroll
    for (int p = 0; p < 2; ++p)
#pragma unroll
        for (int j = 0; j < 16; ++j) acc[p][j] = 0.f;

    for (int icc = 0; icc < 4; ++icc) {
        const int ic0 = icc * 8;
        __syncthreads();
        // stage x tile: sx[row][col][ic], vectorized float4 (1280 float4s)
        for (int t = tid; t < 1280; t += 128) {
            int i4 = t & 1; int u = t >> 1; int col = u % 40; int row = u / 40;
            int r  = oh0 + row; if (r > 69) r = 69;
            int cc = ow0 + col; if (cc > 69) cc = 69;
            ((float4*)sx)[t] =
                *(const float4*)&xn[((size_t)(r * 70 + cc)) * 32 + ic0 + i4 * 4];
        }
        __syncthreads();

        for (int kh = 0; kh < 9; ++kh) {
            const float* sxr = &sx[((ty + kh) * 40 + tx) * 8];
            const float* wr  = W + ((size_t)(kh * 9) * 32 + ic0) * 16;
            for (int kw = 0; kw < 9; ++kw) {
#pragma unroll
                for (int ic = 0; ic < 8; ++ic) {
                    float x0 = sxr[kw * 8 + ic];
                    float x1 = sxr[(kw + 16) * 8 + ic];
                    const float4* wp4 = (const float4*)&wr[(kw * 32 + ic) * 16];
#pragma unroll
                    for (int j4 = 0; j4 < 4; ++j4) {
                        float4 w = wp4[j4];
                        acc[0][j4 * 4 + 0] += x0 * w.x;
                        acc[0][j4 * 4 + 1] += x0 * w.y;
                        acc[0][j4 * 4 + 2] += x0 * w.z;
                        acc[0][j4 * 4 + 3] += x0 * w.w;
                        acc[1][j4 * 4 + 0] += x1 * w.x;
                        acc[1][j4 * 4 + 1] += x1 * w.y;
                        acc[1][j4 * 4 + 2] += x1 * w.z;
                        acc[1][j4 * 4 + 3] += x1 * w.w;
                    }
                }
            }
        }
    }

#pragma unroll
    for (int p = 0; p < 2; ++p) {
        int oh = oh0 + ty, ow = ow0 + tx + p * 16;
        if (oh < 62 && ow < 62) {
            float* yp = y + (((size_t)n * 62 + oh) * 62 + ow) * 16;
#pragma unroll
            for (int j = 0; j < 16; ++j) yp[j] = relu_f(acc[p][j] + bias[j]);
        }
    }
}

// ---------------------------------------------------------------------------
// locally connected v2: block = one output position (i,j), 128 threads
// (2 waves). thread = (b = tid>>2 in 0..31, f4 = tid&3). Weight slab for the
// position is staged global->LDS in STAGES contiguous chunks of GC channels
// (p = c*K2+q is linear in memory, so each chunk is one contiguous span ->
// perfectly coalesced float4 staging, 1KB/wave-inst). Compute reads x as
// c-contiguous float4 from global (L1/L2-resident activations) and weights
// from LDS via ds_read_b128 (16-way same-address broadcast = conflict-free).
// Each thread owns its full K-sum: no cross-lane reduction.
// ---------------------------------------------------------------------------
template <int K, int S, int XD, int OD, int GC>
__global__ __launch_bounds__(128) void k_lc(
    const float* __restrict__ x, const float* __restrict__ W,
    const float* __restrict__ bias, float* __restrict__ y)
{
    constexpr int K2     = K * K;
    constexpr int STAGES = 16 / GC;
    constexpr int SPAN4  = GC * K2 * 4;       // float4s per stage
    __shared__ float sw[GC * K2 * 16];        // <= 25.6 KB

    const int i = blockIdx.y, j = blockIdx.x;
    const int tid = threadIdx.x;
    const int f4 = tid & 3, b = tid >> 2;     // b in 0..31

    const float* xb = x + ((size_t)b * XD * XD + (size_t)(i * S) * XD + (j * S)) * 16;
    const float4* wsrc_base = (const float4*)(W + (size_t)(i * OD + j) * (K2 * 16) * 16);

    float4 acc = make_float4(0.f, 0.f, 0.f, 0.f);

    for (int st = 0; st < STAGES; ++st) {
        const int c0 = st * GC;
        __syncthreads();
        const float4* wsrc = wsrc_base + (size_t)c0 * K2 * 4;
        for (int t = tid; t < SPAN4; t += 128)
            ((float4*)sw)[t] = wsrc[t];
        __syncthreads();

        for (int kh = 0; kh < K; ++kh) {
            const float* xrow = xb + (size_t)(kh * XD) * 16 + c0;
            for (int kw = 0; kw < K; ++kw) {
                const int q = kh * K + kw;
                const float* xr = xrow + kw * 16;
#pragma unroll
                for (int cq = 0; cq < GC / 4; ++cq) {
                    const float4 xv = *(const float4*)(xr + cq * 4);
                    const int cb = cq * 4;
                    fma4(acc, xv.x, *(const float4*)&sw[((cb + 0) * K2 + q) * 16 + f4 * 4]);
                    fma4(acc, xv.y, *(const float4*)&sw[((cb + 1) * K2 + q) * 16 + f4 * 4]);
                    fma4(acc, xv.z, *(const float4*)&sw[((cb + 2) * K2 + q) * 16 + f4 * 4]);
                    fma4(acc, xv.w, *(const float4*)&sw[((cb + 3) * K2 + q) * 16 + f4 * 4]);
                }
            }
        }
    }

    const float4 bv = *(const float4*)(bias + ((size_t)i * OD + j) * 16 + f4 * 4);
    acc.x = relu_f(acc.x + bv.x); acc.y = relu_f(acc.y + bv.y);
    acc.z = relu_f(acc.z + bv.z); acc.w = relu_f(acc.w + bv.w);
    *(float4*)(y + (((size_t)b * OD + i) * OD + j) * 16 + f4 * 4) = acc;
}

// ---------------------------------------------------------------------------
// FC7 split-K: x[32,6400] @ W7[6400,4096] -> partials [16kb][32][4096]
// ---------------------------------------------------------------------------
__global__ __launch_bounds__(256) void k_fc7(
    const float* __restrict__ x, const float* __restrict__ W,
    float* __restrict__ part)
{
    const int o  = blockIdx.x * 256 + threadIdx.x;
    const int k0 = blockIdx.y * 400;
    float acc[32];
#pragma unroll
    for (int b = 0; b < 32; ++b) acc[b] = 0.f;
    const float* wp = W + (size_t)k0 * 4096 + o;
    for (int kk = 0; kk < 400; kk += 2) {
        float w0 = wp[(size_t)kk * 4096];
        float w1 = wp[(size_t)(kk + 1) * 4096];
#pragma unroll
        for (int b = 0; b < 32; ++b) {
            float2 xv = *(const float2*)(x + (size_t)b * 6400 + k0 + kk);
            acc[b] += xv.x * w0 + xv.y * w1;
        }
    }
    float* pp = part + ((size_t)blockIdx.y * 32) * 4096 + o;
#pragma unroll
    for (int b = 0; b < 32; ++b) pp[(size_t)b * 4096] = acc[b];
}

// ---------------------------------------------------------------------------
// reduce partials + b7 + relu, dot with W8, + b8, sigmoid -> out[32]
// ---------------------------------------------------------------------------
__global__ __launch_bounds__(256) void k_fc8(
    const float* __restrict__ part, const float* __restrict__ b7,
    const float* __restrict__ W8, const float* __restrict__ b8,
    float* __restrict__ out)
{
    const int b = blockIdx.x, tid = threadIdx.x;
    float s = 0.f;
    for (int o = tid; o < 4096; o += 256) {
        float v = b7[o];
#pragma unroll
        for (int kb = 0; kb < 16; ++kb) v += part[((size_t)kb * 32 + b) * 4096 + o];
        v = relu_f(v);
        s += v * W8[o];
    }
#pragma unroll
    for (int off = 32; off > 0; off >>= 1) s += __shfl_down(s, off, 64);
    __shared__ float red[4];
    if ((tid & 63) == 0) red[tid >> 6] = s;
    __syncthreads();
    if (tid == 0) {
        float t = red[0] + red[1] + red[2] + red[3] + b8[0];
        out[b] = 1.f / (1.f + expf(-t));
    }
}

// ---------------------------------------------------------------------------
extern "C" void kernel_launch(void* const* d_in, const int* in_sizes, int n_in,
                              void* d_out, int out_size, void* d_ws, size_t ws_size,
                              hipStream_t stream)
{
    (void)in_sizes; (void)n_in; (void)out_size; (void)ws_size;
    const float* x   = (const float*)d_in[0];
    const float* W1  = (const float*)d_in[1];
    const float* b1  = (const float*)d_in[2];
    const float* W3  = (const float*)d_in[3];
    const float* b3  = (const float*)d_in[4];
    const float* LW4 = (const float*)d_in[5];
    const float* Lb4 = (const float*)d_in[6];
    const float* LW5 = (const float*)d_in[7];
    const float* Lb5 = (const float*)d_in[8];
    const float* LW6 = (const float*)d_in[9];
    const float* Lb6 = (const float*)d_in[10];
    const float* W7  = (const float*)d_in[11];
    const float* b7  = (const float*)d_in[12];
    const float* W8  = (const float*)d_in[13];
    const float* b8  = (const float*)d_in[14];
    float* out = (float*)d_out;

    float* ws = (float*)d_ws;
    // workspace layout (floats); y3..p7 overlay dead y1 region.
    float* y1 = ws;                    // 32*142*142*32 = 20,647,936
    float* y2 = ws + 20647936;         // 32*70*70*32   =  5,017,600
    float* y3 = ws;                    // 32*62*62*16   =  1,968,128
    float* y4 = ws + 1968128;          // 32*54*54*16   =  1,492,992
    float* y5 = ws + 3461120;          // 32*24*24*16   =    294,912
    float* y6 = ws + 3756032;          // 32*20*20*16   =    204,800
    float* p7 = ws + 3960832;          // 16*32*4096    =  2,097,152

    k_conv1<<<dim3(5, 9, 32), 256, 0, stream>>>(x, W1, b1, y1);
    k_pool<<<dim3(4900), 256, 0, stream>>>(y1, y2);
    k_conv3<<<dim3(2, 8, 32), 128, 0, stream>>>(y2, W3, b3, y3);
    k_lc<9, 1, 62, 54, 4><<<dim3(54, 54), 128, 0, stream>>>(y3, LW4, Lb4, y4);
    k_lc<7, 2, 54, 24, 8><<<dim3(24, 24), 128, 0, stream>>>(y4, LW5, Lb5, y5);
    k_lc<5, 1, 24, 20, 16><<<dim3(20, 20), 128, 0, stream>>>(y5, LW6, Lb6, y6);
    k_fc7<<<dim3(16, 16), 256, 0, stream>>>(y6, W7, p7);
    k_fc8<<<dim3(32), 256, 0, stream>>>(p7, b7, W8, b8, out);
}

// Round 2
// 1163.100 us; speedup vs baseline: 1.2463x; 1.2463x over previous
//
#include <hip/hip_runtime.h>
#include <math.h>

#define DEV_INLINE __device__ __forceinline__

DEV_INLINE float relu_f(float v) { return v > 0.f ? v : 0.f; }

DEV_INLINE void fma4(float4& a, float s, const float4& v) {
    a.x += s * v.x; a.y += s * v.y; a.z += s * v.z; a.w += s * v.w;
}

// ---------------------------------------------------------------------------
// conv1: x[32,152,152,3] * W[11,11,3,32] + b, relu -> y[32,142,142,32]
// block 256 (16ty x 16tx), tile 16 oh x 32 ow, thread: 2 ow x 32 oc.
// Weights staged per-kh chunk (1056 floats = 4.2 KB) -> total LDS 17.3 KB
// -> ~5 blocks/CU (20 waves/CU) instead of 2 blocks (8 waves).
// Weight ds_reads are wave-uniform float4 -> broadcast (cheap); x reads are
// [row][col][3] at lane-stride 3 -> max 2-way bank alias (free).
// ---------------------------------------------------------------------------
__global__ __launch_bounds__(256) void k_conv1(
    const float* __restrict__ x, const float* __restrict__ W,
    const float* __restrict__ b, float* __restrict__ y)
{
    __shared__ float sx[26 * 42 * 3];    // 3276 floats = 13.1 KB
    __shared__ float swc[11 * 3 * 32];   // 1056 floats =  4.2 KB (per-kh chunk)
    const int n   = blockIdx.z;
    const int oh0 = blockIdx.y * 16;
    const int ow0 = blockIdx.x * 32;
    const int tid = threadIdx.x;

    const float* xn = x + (size_t)n * 152 * 152 * 3;
    for (int i = tid; i < 26 * 42 * 3; i += 256) {
        int c = i % 3; int t = i / 3; int col = t % 42; int row = t / 42;
        int r  = oh0 + row; if (r > 151) r = 151;
        int cc = ow0 + col; if (cc > 151) cc = 151;
        sx[i] = xn[(r * 152 + cc) * 3 + c];
    }

    const int ty = tid >> 4, tx = tid & 15;
    float acc[2][32];
#pragma unroll
    for (int p = 0; p < 2; ++p)
#pragma unroll
        for (int j = 0; j < 32; ++j) acc[p][j] = 0.f;

    for (int kh = 0; kh < 11; ++kh) {
        __syncthreads();   // prev-kh compute done (also covers sx staging at kh=0)
        const float4* wsrc = (const float4*)W + kh * 264;
        for (int t = tid; t < 264; t += 256) ((float4*)swc)[t] = wsrc[t];
        __syncthreads();

        const float* sxr = &sx[((ty + kh) * 42 + tx) * 3];
        for (int kw = 0; kw < 11; ++kw) {
#pragma unroll
            for (int ic = 0; ic < 3; ++ic) {
                float x0 = sxr[(kw) * 3 + ic];
                float x1 = sxr[(kw + 16) * 3 + ic];
                const float4* wp4 = (const float4*)&swc[(kw * 3 + ic) * 32];
#pragma unroll
                for (int j4 = 0; j4 < 8; ++j4) {
                    float4 w = wp4[j4];
                    acc[0][j4 * 4 + 0] += x0 * w.x;
                    acc[0][j4 * 4 + 1] += x0 * w.y;
                    acc[0][j4 * 4 + 2] += x0 * w.z;
                    acc[0][j4 * 4 + 3] += x0 * w.w;
                    acc[1][j4 * 4 + 0] += x1 * w.x;
                    acc[1][j4 * 4 + 1] += x1 * w.y;
                    acc[1][j4 * 4 + 2] += x1 * w.z;
                    acc[1][j4 * 4 + 3] += x1 * w.w;
                }
            }
        }
    }

#pragma unroll
    for (int p = 0; p < 2; ++p) {
        int oh = oh0 + ty, ow = ow0 + tx + p * 16;
        if (oh < 142 && ow < 142) {
            float* yp = y + (((size_t)n * 142 + oh) * 142 + ow) * 32;
#pragma unroll
            for (int j = 0; j < 32; ++j) yp[j] = relu_f(acc[p][j] + b[j]);
        }
    }
}

// ---------------------------------------------------------------------------
// maxpool 3x3 s2: y1[32,142,142,32] -> y2[32,70,70,32]
// ---------------------------------------------------------------------------
__global__ void k_pool(const float* __restrict__ x, float* __restrict__ y)
{
    int idx = blockIdx.x * 256 + threadIdx.x;  // over 32*70*70*8 (c in float4s)
    if (idx >= 32 * 70 * 70 * 8) return;
    int c4 = idx & 7; int t = idx >> 3;
    int pw = t % 70; t /= 70; int ph = t % 70; int n = t / 70;
    const float* xp = x + (((size_t)n * 142 + ph * 2) * 142 + pw * 2) * 32 + c4 * 4;
    float4 m = make_float4(-1e30f, -1e30f, -1e30f, -1e30f);
#pragma unroll
    for (int r = 0; r < 3; ++r) {
#pragma unroll
        for (int cc = 0; cc < 3; ++cc) {
            float4 v = *(const float4*)(xp + ((size_t)r * 142 + cc) * 32);
            m.x = fmaxf(m.x, v.x); m.y = fmaxf(m.y, v.y);
            m.z = fmaxf(m.z, v.z); m.w = fmaxf(m.w, v.w);
        }
    }
    *(float4*)(y + (size_t)idx * 4) = m;
}

// ---------------------------------------------------------------------------
// conv3: y2[32,70,70,32] * W[9,9,32,16] + b, relu -> y3[32,62,62,16]
// block 256 = 2 wave-pairs: h = tid>>7 picks oc half (wave-uniform), within
// half: 8ty x 16tx, thread: 2 ow x 8 oc. Grid (2,8,32)=512 blocks -> 2
// blocks/CU -> 8 waves/CU (2x round-0). LDS: sw icc-chunk 41.5 KB (broadcast
// reads) + sx [16][40][9] 23 KB (ic padded 8->9: lane bank = 9*tx+8*ty mod 32,
// max 2-way alias = free; unpadded was 16-way conflict).
// ---------------------------------------------------------------------------
__global__ __launch_bounds__(256) void k_conv3(
    const float* __restrict__ x, const float* __restrict__ W,
    const float* __restrict__ bias, float* __restrict__ y)
{
    __shared__ float sw[81 * 8 * 16];   // 10368 floats = 41.5 KB
    __shared__ float sx[16 * 40 * 9];   // 5760 floats  = 23.0 KB
    const int n   = blockIdx.z;
    const int oh0 = blockIdx.y * 8;
    const int ow0 = blockIdx.x * 32;
    const int tid = threadIdx.x;
    const int h   = tid >> 7;            // 0/1, wave-uniform oc half
    const int rem = tid & 127;
    const int ty = rem >> 4, tx = rem & 15;
    const float* xn = x + (size_t)n * 70 * 70 * 32;

    float acc[2][8];
#pragma unroll
    for (int p = 0; p < 2; ++p)
#pragma unroll
        for (int j = 0; j < 8; ++j) acc[p][j] = 0.f;

    for (int icc = 0; icc < 4; ++icc) {
        const int ic0 = icc * 8;
        __syncthreads();
        // stage W chunk: sw[q][ic][oc], 2592 float4s, coalesced
        const float4* W4 = (const float4*)W;
        for (int t = tid; t < 2592; t += 256) {
            int oc4 = t & 3; int u = t >> 2; int ic = u & 7; int q = u >> 3;
            ((float4*)sw)[t] = W4[(q * 32 + ic0 + ic) * 4 + oc4];
        }
        // stage x tile: global float4 (coalesced), scatter to padded sx
        for (int t = tid; t < 1280; t += 256) {
            int half = t & 1; int pix = t >> 1; int col = pix % 40; int row = pix / 40;
            int r  = oh0 + row; if (r > 69) r = 69;
            int cc = ow0 + col; if (cc > 69) cc = 69;
            float4 v = *(const float4*)&xn[((size_t)(r * 70 + cc)) * 32 + ic0 + half * 4];
            float* d = &sx[(row * 40 + col) * 9 + half * 4];
            d[0] = v.x; d[1] = v.y; d[2] = v.z; d[3] = v.w;
        }
        __syncthreads();

        for (int kh = 0; kh < 9; ++kh) {
            const float* sxr = &sx[((ty + kh) * 40 + tx) * 9];
            for (int kw = 0; kw < 9; ++kw) {
                const int q = kh * 9 + kw;
#pragma unroll
                for (int ic = 0; ic < 8; ++ic) {
                    float x0 = sxr[(kw) * 9 + ic];
                    float x1 = sxr[(kw + 16) * 9 + ic];
                    const float4* wp4 = (const float4*)&sw[(q * 8 + ic) * 16 + h * 8];
                    float4 w0 = wp4[0];
                    float4 w1 = wp4[1];
                    acc[0][0] += x0 * w0.x; acc[0][1] += x0 * w0.y;
                    acc[0][2] += x0 * w0.z; acc[0][3] += x0 * w0.w;
                    acc[0][4] += x0 * w1.x; acc[0][5] += x0 * w1.y;
                    acc[0][6] += x0 * w1.z; acc[0][7] += x0 * w1.w;
                    acc[1][0] += x1 * w0.x; acc[1][1] += x1 * w0.y;
                    acc[1][2] += x1 * w0.z; acc[1][3] += x1 * w0.w;
                    acc[1][4] += x1 * w1.x; acc[1][5] += x1 * w1.y;
                    acc[1][6] += x1 * w1.z; acc[1][7] += x1 * w1.w;
                }
            }
        }
    }

#pragma unroll
    for (int p = 0; p < 2; ++p) {
        int oh = oh0 + ty, ow = ow0 + tx + p * 16;
        if (oh < 62 && ow < 62) {
            float* yp = y + (((size_t)n * 62 + oh) * 62 + ow) * 16 + h * 8;
            const float* bp = bias + h * 8;
#pragma unroll
            for (int j = 0; j < 8; ++j) yp[j] = relu_f(acc[p][j] + bp[j]);
        }
    }
}

// ---------------------------------------------------------------------------
// locally connected v2: block = one output position (i,j), 128 threads
// (2 waves). thread = (b = tid>>2 in 0..31, f4 = tid&3). Weight slab staged
// global->LDS in contiguous float4 chunks (coalesced); compute reads x as
// c-contiguous float4 from global (L2-resident) and weights from LDS via
// 16-way same-address broadcast. Each thread owns its full K-sum.
// ---------------------------------------------------------------------------
template <int K, int S, int XD, int OD, int GC>
__global__ __launch_bounds__(128) void k_lc(
    const float* __restrict__ x, const float* __restrict__ W,
    const float* __restrict__ bias, float* __restrict__ y)
{
    constexpr int K2     = K * K;
    constexpr int STAGES = 16 / GC;
    constexpr int SPAN4  = GC * K2 * 4;       // float4s per stage
    __shared__ float sw[GC * K2 * 16];        // <= 25.6 KB

    const int i = blockIdx.y, j = blockIdx.x;
    const int tid = threadIdx.x;
    const int f4 = tid & 3, b = tid >> 2;     // b in 0..31

    const float* xb = x + ((size_t)b * XD * XD + (size_t)(i * S) * XD + (j * S)) * 16;
    const float4* wsrc_base = (const float4*)(W + (size_t)(i * OD + j) * (K2 * 16) * 16);

    float4 acc = make_float4(0.f, 0.f, 0.f, 0.f);

    for (int st = 0; st < STAGES; ++st) {
        const int c0 = st * GC;
        __syncthreads();
        const float4* wsrc = wsrc_base + (size_t)c0 * K2 * 4;
        for (int t = tid; t < SPAN4; t += 128)
            ((float4*)sw)[t] = wsrc[t];
        __syncthreads();

        for (int kh = 0; kh < K; ++kh) {
            const float* xrow = xb + (size_t)(kh * XD) * 16 + c0;
            for (int kw = 0; kw < K; ++kw) {
                const int q = kh * K + kw;
                const float* xr = xrow + kw * 16;
#pragma unroll
                for (int cq = 0; cq < GC / 4; ++cq) {
                    const float4 xv = *(const float4*)(xr + cq * 4);
                    const int cb = cq * 4;
                    fma4(acc, xv.x, *(const float4*)&sw[((cb + 0) * K2 + q) * 16 + f4 * 4]);
                    fma4(acc, xv.y, *(const float4*)&sw[((cb + 1) * K2 + q) * 16 + f4 * 4]);
                    fma4(acc, xv.z, *(const float4*)&sw[((cb + 2) * K2 + q) * 16 + f4 * 4]);
                    fma4(acc, xv.w, *(const float4*)&sw[((cb + 3) * K2 + q) * 16 + f4 * 4]);
                }
            }
        }
    }

    const float4 bv = *(const float4*)(bias + ((size_t)i * OD + j) * 16 + f4 * 4);
    acc.x = relu_f(acc.x + bv.x); acc.y = relu_f(acc.y + bv.y);
    acc.z = relu_f(acc.z + bv.z); acc.w = relu_f(acc.w + bv.w);
    *(float4*)(y + (((size_t)b * OD + i) * OD + j) * 16 + f4 * 4) = acc;
}

// ---------------------------------------------------------------------------
// FC7 split-K: x[32,6400] @ W7[6400,4096] -> partials [16kb][32][4096]
// ---------------------------------------------------------------------------
__global__ __launch_bounds__(256) void k_fc7(
    const float* __restrict__ x, const float* __restrict__ W,
    float* __restrict__ part)
{
    const int o  = blockIdx.x * 256 + threadIdx.x;
    const int k0 = blockIdx.y * 400;
    float acc[32];
#pragma unroll
    for (int b = 0; b < 32; ++b) acc[b] = 0.f;
    const float* wp = W + (size_t)k0 * 4096 + o;
    for (int kk = 0; kk < 400; kk += 2) {
        float w0 = wp[(size_t)kk * 4096];
        float w1 = wp[(size_t)(kk + 1) * 4096];
#pragma unroll
        for (int b = 0; b < 32; ++b) {
            float2 xv = *(const float2*)(x + (size_t)b * 6400 + k0 + kk);
            acc[b] += xv.x * w0 + xv.y * w1;
        }
    }
    float* pp = part + ((size_t)blockIdx.y * 32) * 4096 + o;
#pragma unroll
    for (int b = 0; b < 32; ++b) pp[(size_t)b * 4096] = acc[b];
}

// ---------------------------------------------------------------------------
// reduce partials + b7 + relu, dot with W8, + b8, sigmoid -> out[32]
// ---------------------------------------------------------------------------
__global__ __launch_bounds__(256) void k_fc8(
    const float* __restrict__ part, const float* __restrict__ b7,
    const float* __restrict__ W8, const float* __restrict__ b8,
    float* __restrict__ out)
{
    const int b = blockIdx.x, tid = threadIdx.x;
    float s = 0.f;
    for (int o = tid; o < 4096; o += 256) {
        float v = b7[o];
#pragma unroll
        for (int kb = 0; kb < 16; ++kb) v += part[((size_t)kb * 32 + b) * 4096 + o];
        v = relu_f(v);
        s += v * W8[o];
    }
#pragma unroll
    for (int off = 32; off > 0; off >>= 1) s += __shfl_down(s, off, 64);
    __shared__ float red[4];
    if ((tid & 63) == 0) red[tid >> 6] = s;
    __syncthreads();
    if (tid == 0) {
        float t = red[0] + red[1] + red[2] + red[3] + b8[0];
        out[b] = 1.f / (1.f + expf(-t));
    }
}

// ---------------------------------------------------------------------------
extern "C" void kernel_launch(void* const* d_in, const int* in_sizes, int n_in,
                              void* d_out, int out_size, void* d_ws, size_t ws_size,
                              hipStream_t stream)
{
    (void)in_sizes; (void)n_in; (void)out_size; (void)ws_size;
    const float* x   = (const float*)d_in[0];
    const float* W1  = (const float*)d_in[1];
    const float* b1  = (const float*)d_in[2];
    const float* W3  = (const float*)d_in[3];
    const float* b3  = (const float*)d_in[4];
    const float* LW4 = (const float*)d_in[5];
    const float* Lb4 = (const float*)d_in[6];
    const float* LW5 = (const float*)d_in[7];
    const float* Lb5 = (const float*)d_in[8];
    const float* LW6 = (const float*)d_in[9];
    const float* Lb6 = (const float*)d_in[10];
    const float* W7  = (const float*)d_in[11];
    const float* b7  = (const float*)d_in[12];
    const float* W8  = (const float*)d_in[13];
    const float* b8  = (const float*)d_in[14];
    float* out = (float*)d_out;

    float* ws = (float*)d_ws;
    // workspace layout (floats); y3..p7 overlay dead y1 region.
    float* y1 = ws;                    // 32*142*142*32 = 20,647,936
    float* y2 = ws + 20647936;         // 32*70*70*32   =  5,017,600
    float* y3 = ws;                    // 32*62*62*16   =  1,968,128
    float* y4 = ws + 1968128;          // 32*54*54*16   =  1,492,992
    float* y5 = ws + 3461120;          // 32*24*24*16   =    294,912
    float* y6 = ws + 3756032;          // 32*20*20*16   =    204,800
    float* p7 = ws + 3960832;          // 16*32*4096    =  2,097,152

    k_conv1<<<dim3(5, 9, 32), 256, 0, stream>>>(x, W1, b1, y1);
    k_pool<<<dim3(4900), 256, 0, stream>>>(y1, y2);
    k_conv3<<<dim3(2, 8, 32), 256, 0, stream>>>(y2, W3, b3, y3);
    k_lc<9, 1, 62, 54, 4><<<dim3(54, 54), 128, 0, stream>>>(y3, LW4, Lb4, y4);
    k_lc<7, 2, 54, 24, 8><<<dim3(24, 24), 128, 0, stream>>>(y4, LW5, Lb5, y5);
    k_lc<5, 1, 24, 20, 16><<<dim3(20, 20), 128, 0, stream>>>(y5, LW6, Lb6, y6);
    k_fc7<<<dim3(16, 16), 256, 0, stream>>>(y6, W7, p7);
    k_fc8<<<dim3(32), 256, 0, stream>>>(p7, b7, W8, b8, out);
}